// Round 7
// baseline (217.225 us; speedup 1.0000x reference)
//
#include <hip/hip_runtime.h>
#include <hip/hip_bf16.h>
#include <math.h>

#define NROWS 131072   // B*T = 32*4096
#define KC    512      // codebook size
#define DD    64       // embedding dim
#define NELEM (NROWS * DD)

#define OUT_IDX_OFF  NELEM
#define OUT_LOSS_OFF (NELEM + NROWS)

#define MARGIN 3e-5f   // r0-validated: covers bf16 hi/lo screen error (~3e-6) with margin

// d_ws byte offsets
#define WSO_CNT   0                        // int   flagged-row count
#define WSO_DONE  4                        // int   refine blocks-done count
#define WSO_LOSS  8                        // float loss accumulator
#define WSO_WNORM 64                       // float wnorm_np[512]
#define WSO_BH    4096                     // bf16 frags W-hi: 32 tiles x 2 kh x 64 lanes x 8 = 64 KB
#define WSO_BL    (WSO_BH + 65536)         // bf16 frags W-lo: 64 KB
#define WSO_WT    (WSO_BL + 65536)         // float Wt[64][512] transposed codebook, 128 KB
#define WSO_LIST  (WSO_WT + 131072)        // int flagList[FLAG_CAP]
#define FLAG_CAP  32768                    // ~40x the observed ~800 flags at margin 3e-5

typedef __attribute__((ext_vector_type(8))) short short8;
typedef __attribute__((ext_vector_type(4))) float f32x4;

// ---------------------------------------------------------------------------
// bf16 helpers (RNE via __float2bfloat16)
// ---------------------------------------------------------------------------
__device__ __forceinline__ short f2bf_bits(float f) {
  __hip_bfloat16 h = __float2bfloat16(f);
  short s; __builtin_memcpy(&s, &h, 2); return s;
}
__device__ __forceinline__ float bfbits2f(short s) {
  __hip_bfloat16 h; __builtin_memcpy(&h, &s, 2);
  return __bfloat162float(h);
}
// split 8 consecutive f32 into bf16 hi + bf16 lo(residual)
__device__ __forceinline__ void cvt8(const float* __restrict__ p, short8& hi, short8& lo) {
#pragma unroll
  for (int j = 0; j < 8; j++) {
    float f = p[j];
    short hb = f2bf_bits(f);
    float r = f - bfbits2f(hb);
    hi[j] = hb;
    lo[j] = f2bf_bits(r);
  }
}

// ---------------------------------------------------------------------------
// numpy's pairwise sum of squares for 64 contiguous f32 (8-accumulator tree).
// contract(off) REQUIRED (hipcc default -ffp-contract=fast would fuse).
// ---------------------------------------------------------------------------
__device__ __forceinline__ float np_sumsq64(const float* __restrict__ p) {
#pragma clang fp contract(off)
  float r0 = p[0] * p[0], r1 = p[1] * p[1], r2 = p[2] * p[2], r3 = p[3] * p[3];
  float r4 = p[4] * p[4], r5 = p[5] * p[5], r6 = p[6] * p[6], r7 = p[7] * p[7];
  for (int i = 8; i < 64; i += 8) {
    r0 = r0 + p[i + 0] * p[i + 0];
    r1 = r1 + p[i + 1] * p[i + 1];
    r2 = r2 + p[i + 2] * p[i + 2];
    r3 = r3 + p[i + 3] * p[i + 3];
    r4 = r4 + p[i + 4] * p[i + 4];
    r5 = r5 + p[i + 5] * p[i + 5];
    r6 = r6 + p[i + 6] * p[i + 6];
    r7 = r7 + p[i + 7] * p[i + 7];
  }
  return ((r0 + r1) + (r2 + r3)) + ((r4 + r5) + (r6 + r7));
}

// ---------------------------------------------------------------------------
// Kernel 0: prep — ROUND-7: 128 blocks (was 16: a 256-CU chip at 6%
// utilization; the Wt transpose gather made it ~30-40us of the residual).
//   gtid 0..32767: Wt transpose, COALESCED reads: wave reads W[k][0..63]
//     contiguous (256B), scatters writes Wt[d][k] (stores don't stall).
//   gtid < 4096: W -> MFMA-B-fragment bf16 hi/lo (mapping unchanged).
//   gtid < 512:  wnorm_np[k] (numpy-exact).
//   gtid == 0:   zero ws scalars (absorbs memset dispatch).
// ---------------------------------------------------------------------------
__global__ void k_prep(const float* __restrict__ W, short8* __restrict__ Bh,
                       short8* __restrict__ Bl, float* __restrict__ wnorm,
                       float* __restrict__ Wt, int* __restrict__ flagCnt,
                       int* __restrict__ doneCnt, float* __restrict__ lossSum) {
  int gtid = blockIdx.x * blockDim.x + threadIdx.x;  // 0..32767
  if (gtid == 0) { *flagCnt = 0; *doneCnt = 0; *lossSum = 0.0f; }

  // transposed codebook: coalesced read, scattered write
  {
    int k = gtid >> 6, d = gtid & 63;
    Wt[(d << 9) + k] = W[(k << 6) + d];
  }

  if (gtid < 4096) {
    int t = gtid >> 7, rem = gtid & 127;
    int h = rem >> 6, L = rem & 63;
    int cw = (t << 4) + (L & 15);
    int dbase = (h << 5) + ((L >> 4) << 3);
    short8 hi, lo;
    cvt8(W + (cw << 6) + dbase, hi, lo);
    Bh[gtid] = hi;  // gtid == ((t*2+h)*64 + L)
    Bl[gtid] = lo;
    if (gtid < KC) wnorm[gtid] = np_sumsq64(W + (gtid << 6));
  }
}

// ---------------------------------------------------------------------------
// Kernel 1: fused MFMA screen + argmin + epilogue — ROUND-0 VERBATIM
// (the one config measured at 93.5us; every structural edit of it in
// r1/r2/r3/r4/r6 regressed: 101/463/137/124us. Do not touch.)
// Wave handles 64 rows (4 M-tiles of 16). A frags built in-register from z
// (split bf16 hi/lo); B frags streamed from prepped global arrays (L2-hot).
// score_k = wnorm_np[k] - 2*(zh.wh + zl.wh + zh.wl)  [drops row-const ||z||^2;
// error <= ~3e-6 abs, covered by MARGIN]. Per-lane best/second/idx over its
// col slice (ascending k -> strict < keeps first index), xor-butterfly merge
// over the 16 col-lanes with index tie-break. Near-ties flagged for refine.
// Then writes z_q_st, idx-as-float, and loss partial for all 64 rows.
// ---------------------------------------------------------------------------
__global__ __launch_bounds__(256) void k_screen(
    const float* __restrict__ z, const float* __restrict__ W,
    const short8* __restrict__ Bh, const short8* __restrict__ Bl,
    const float* __restrict__ wnorm, float* __restrict__ out,
    int* __restrict__ flagList, int* __restrict__ flagCnt,
    float* __restrict__ lossSum) {
  const int lane = threadIdx.x & 63;
  const int wave = threadIdx.x >> 6;
  const int rowBase = blockIdx.x * 256 + wave * 64;
  const int m = lane & 15, quad = lane >> 4;

  // ---- A fragments: zh/zl for 4 M-tiles x 2 k-halves ----
  short8 Ah[4][2], Al[4][2];
#pragma unroll
  for (int mt = 0; mt < 4; mt++) {
    const float* zp = z + (size_t)(rowBase + (mt << 4) + m) * DD + (quad << 3);
#pragma unroll
    for (int h = 0; h < 2; h++) cvt8(zp + (h << 5), Ah[mt][h], Al[mt][h]);
  }

  float b1[4][4], b2[4][4];
  int bi[4][4];
#pragma unroll
  for (int mt = 0; mt < 4; mt++)
#pragma unroll
    for (int r = 0; r < 4; r++) { b1[mt][r] = 1e30f; b2[mt][r] = 1e30f; bi[mt][r] = 0; }

  // ---- main loop over 32 codeword tiles ----
  for (int t = 0; t < 32; t++) {
    short8 Bhf[2], Blf[2];
#pragma unroll
    for (int h = 0; h < 2; h++) {
      Bhf[h] = Bh[((t * 2 + h) << 6) + lane];
      Blf[h] = Bl[((t * 2 + h) << 6) + lane];
    }
    float wn = wnorm[(t << 4) + m];

    f32x4 acc[4] = {{0.f, 0.f, 0.f, 0.f}, {0.f, 0.f, 0.f, 0.f},
                    {0.f, 0.f, 0.f, 0.f}, {0.f, 0.f, 0.f, 0.f}};
#pragma unroll
    for (int h = 0; h < 2; h++) {
#pragma unroll
      for (int mt = 0; mt < 4; mt++)
        acc[mt] = __builtin_amdgcn_mfma_f32_16x16x32_bf16(Ah[mt][h], Bhf[h], acc[mt], 0, 0, 0);
#pragma unroll
      for (int mt = 0; mt < 4; mt++)
        acc[mt] = __builtin_amdgcn_mfma_f32_16x16x32_bf16(Al[mt][h], Bhf[h], acc[mt], 0, 0, 0);
#pragma unroll
      for (int mt = 0; mt < 4; mt++)
        acc[mt] = __builtin_amdgcn_mfma_f32_16x16x32_bf16(Ah[mt][h], Blf[h], acc[mt], 0, 0, 0);
    }

    int colv = (t << 4) + m;
#pragma unroll
    for (int mt = 0; mt < 4; mt++)
#pragma unroll
      for (int r = 0; r < 4; r++) {
        float s = fmaf(-2.0f, acc[mt][r], wn);
        if (s < b1[mt][r]) { b2[mt][r] = b1[mt][r]; b1[mt][r] = s; bi[mt][r] = colv; }
        else b2[mt][r] = fminf(b2[mt][r], s);
      }
  }

  // ---- merge across the 16 col-lanes (xor butterfly within quad group) ----
#pragma unroll
  for (int off = 1; off < 16; off <<= 1) {
#pragma unroll
    for (int mt = 0; mt < 4; mt++)
#pragma unroll
      for (int r = 0; r < 4; r++) {
        float o1 = __shfl_xor(b1[mt][r], off, 64);
        float o2 = __shfl_xor(b2[mt][r], off, 64);
        int oi = __shfl_xor(bi[mt][r], off, 64);
        if (o1 < b1[mt][r] || (o1 == b1[mt][r] && oi < bi[mt][r])) {
          b2[mt][r] = fminf(b1[mt][r], o2);
          b1[mt][r] = o1; bi[mt][r] = oi;
        } else {
          b2[mt][r] = fminf(b2[mt][r], o1);
        }
      }
  }

  // ---- fused epilogue: z_q_st, idx, loss, flags for this wave's 64 rows ----
  float lossAcc = 0.f;
#pragma unroll
  for (int mt = 0; mt < 4; mt++)
#pragma unroll
    for (int lr = 0; lr < 16; lr++) {
      const int q = lr >> 2, r = lr & 3;
      int ki = __shfl(bi[mt][r], q << 4, 64);
      float b1r = __shfl(b1[mt][r], q << 4, 64);
      float b2r = __shfl(b2[mt][r], q << 4, 64);
      int row = rowBase + (mt << 4) + lr;
      float zv = z[(size_t)row * DD + lane];
      float w = W[(ki << 6) + lane];
      float tt = w - zv;
      float o = zv + tt;  // matches reference z + (z_q - z)
      out[(size_t)row * DD + lane] = o;
      float dl = zv - o;
      lossAcc = fmaf(dl, dl, lossAcc);
      if (lane == 0) {
        out[OUT_IDX_OFF + row] = (float)ki;
        if (b2r - b1r < MARGIN) {
          int slot = atomicAdd(flagCnt, 1);
          if (slot < FLAG_CAP) flagList[slot] = row;
        }
      }
    }

#pragma unroll
  for (int off = 1; off < 64; off <<= 1) lossAcc += __shfl_xor(lossAcc, off, 64);
  if (lane == 0) atomicAdd(lossSum, lossAcc);
}

// ---------------------------------------------------------------------------
// Kernel 2: numpy-f32 replication for flagged rows + patch out/loss.
// dist_np = fl32( fl32(A + wnp[k]) - fl32(2*C) ), C = f64 dot rounded once.
// ROUND-7: W read through TRANSPOSED Wt -> lane-coalesced (k=lane+64j
// contiguous; r5 showed the row-major W gather = 64 cache lines per load
// instruction = 172-274us at high flag counts).
// Tail: last-block-done pattern finalizes the loss (absorbs k_finalize).
// ---------------------------------------------------------------------------
__global__ void k_refine(const float* __restrict__ z, const float* __restrict__ W,
                         const float* __restrict__ Wt, const float* __restrict__ wnp,
                         float* __restrict__ out,
                         const int* __restrict__ flagList,
                         const int* __restrict__ flagCnt,
                         float* __restrict__ lossSum, int* __restrict__ doneCnt) {
  int nflag = *flagCnt;
  if (nflag > FLAG_CAP) nflag = FLAG_CAP;
  int lane = threadIdx.x & 63;
  int wave = (blockIdx.x * blockDim.x + threadIdx.x) >> 6;
  int nWaves = (gridDim.x * blockDim.x) >> 6;

  for (int f = wave; f < nflag; f += nWaves) {
    int row = flagList[f];
    const float* zr = z + (size_t)row * DD;
    float A = np_sumsq64(zr);

    float best = 1e30f;
    int bk = 0x7fffffff;
#pragma unroll
    for (int j = 0; j < KC / 64; j++) {
      int k = lane + (j << 6);
      double cd = 0.0;
      for (int d = 0; d < DD; d++)
        cd = fma((double)zr[d], (double)Wt[(d << 9) + k], cd);
      float twoC = (float)(2.0 * cd);
      float dist;
      {
#pragma clang fp contract(off)
        float t1 = A + wnp[k];
        dist = t1 - twoC;
      }
      if (dist < best || (dist == best && k < bk)) { best = dist; bk = k; }
    }
#pragma unroll
    for (int off = 1; off < 64; off <<= 1) {
      float ov = __shfl_xor(best, off, 64);
      int ok = __shfl_xor(bk, off, 64);
      if (ov < best || (ov == best && ok < bk)) { best = ov; bk = ok; }
    }

    int kold = (int)out[OUT_IDX_OFF + row];
    if (bk != kold) {
      float zv = zr[lane];
      float wN = W[(bk << 6) + lane];
      float oOld = out[(size_t)row * DD + lane];
      float tN = wN - zv;
      float oN = zv + tN;
      out[(size_t)row * DD + lane] = oN;
      float dN = zv - oN, dO = zv - oOld;
      float delta = dN * dN - dO * dO;
#pragma unroll
      for (int off = 1; off < 64; off <<= 1) delta += __shfl_xor(delta, off, 64);
      if (lane == 0) {
        atomicAdd(lossSum, delta);
        out[OUT_IDX_OFF + row] = (float)bk;
      }
    }
  }

  // ---- finalize: last block to arrive writes the loss scalar ----
  __syncthreads();
  if (threadIdx.x == 0) {
    __threadfence();
    int d = atomicAdd(doneCnt, 1);
    if (d == (int)gridDim.x - 1) {
      float s = atomicAdd(lossSum, 0.0f);  // atomic read sees all prior adds
      out[OUT_LOSS_OFF] = 0.25f * s / (float)NELEM;
    }
  }
}

extern "C" void kernel_launch(void* const* d_in, const int* in_sizes, int n_in,
                              void* d_out, int out_size, void* d_ws, size_t ws_size,
                              hipStream_t stream) {
  const float* z = (const float*)d_in[0];
  const float* W = (const float*)d_in[1];
  float* out = (float*)d_out;
  char* ws = (char*)d_ws;

  int* flagCnt = (int*)(ws + WSO_CNT);
  int* doneCnt = (int*)(ws + WSO_DONE);
  float* lossSum = (float*)(ws + WSO_LOSS);
  float* wnorm = (float*)(ws + WSO_WNORM);
  short8* Bh = (short8*)(ws + WSO_BH);
  short8* Bl = (short8*)(ws + WSO_BL);
  float* Wt = (float*)(ws + WSO_WT);
  int* flagList = (int*)(ws + WSO_LIST);

  k_prep<<<128, 256, 0, stream>>>(W, Bh, Bl, wnorm, Wt, flagCnt, doneCnt, lossSum);
  k_screen<<<NROWS / 256, 256, 0, stream>>>(z, W, Bh, Bl, wnorm, out,
                                            flagList, flagCnt, lossSum);
  k_refine<<<256, 256, 0, stream>>>(z, W, Wt, wnorm, out, flagList, flagCnt,
                                    lossSum, doneCnt);
}

// Round 8
// 212.549 us; speedup vs baseline: 1.0220x; 1.0220x over previous
//
#include <hip/hip_runtime.h>
#include <hip/hip_bf16.h>
#include <math.h>

#define NROWS 131072   // B*T = 32*4096
#define KC    512      // codebook size
#define DD    64       // embedding dim
#define NELEM (NROWS * DD)

#define OUT_IDX_OFF  NELEM
#define OUT_LOSS_OFF (NELEM + NROWS)

#define MARGIN 3e-5f   // r0-validated: covers bf16 hi/lo screen error (~3e-6) with margin

// d_ws byte offsets
#define WSO_CNT   0                        // int   flagged-row count
#define WSO_DONE  4                        // int   refine blocks-done count
#define WSO_LOSS  8                        // float loss accumulator
#define WSO_WNORM 64                       // float wnorm_np[512]
#define WSO_BH    4096                     // bf16 frags W-hi: 32 tiles x 2 kh x 64 lanes x 8 = 64 KB
#define WSO_BL    (WSO_BH + 65536)         // bf16 frags W-lo: 64 KB
#define WSO_WT    (WSO_BL + 65536)         // float Wt[64][512] transposed codebook, 128 KB
#define WSO_LIST  (WSO_WT + 131072)        // int flagList[FLAG_CAP]
#define FLAG_CAP  32768

typedef __attribute__((ext_vector_type(8))) short short8;
typedef __attribute__((ext_vector_type(4))) float f32x4;

// ---------------------------------------------------------------------------
// bf16 helpers (RNE via __float2bfloat16)
// ---------------------------------------------------------------------------
__device__ __forceinline__ short f2bf_bits(float f) {
  __hip_bfloat16 h = __float2bfloat16(f);
  short s; __builtin_memcpy(&s, &h, 2); return s;
}
__device__ __forceinline__ float bfbits2f(short s) {
  __hip_bfloat16 h; __builtin_memcpy(&h, &s, 2);
  return __bfloat162float(h);
}
// split 8 consecutive f32 into bf16 hi + bf16 lo(residual)
__device__ __forceinline__ void cvt8(const float* __restrict__ p, short8& hi, short8& lo) {
#pragma unroll
  for (int j = 0; j < 8; j++) {
    float f = p[j];
    short hb = f2bf_bits(f);
    float r = f - bfbits2f(hb);
    hi[j] = hb;
    lo[j] = f2bf_bits(r);
  }
}

// ---------------------------------------------------------------------------
// numpy's pairwise sum of squares for 64 contiguous f32 (8-accumulator tree).
// contract(off) REQUIRED (hipcc default -ffp-contract=fast would fuse).
// ---------------------------------------------------------------------------
__device__ __forceinline__ float np_sumsq64(const float* __restrict__ p) {
#pragma clang fp contract(off)
  float r0 = p[0] * p[0], r1 = p[1] * p[1], r2 = p[2] * p[2], r3 = p[3] * p[3];
  float r4 = p[4] * p[4], r5 = p[5] * p[5], r6 = p[6] * p[6], r7 = p[7] * p[7];
  for (int i = 8; i < 64; i += 8) {
    r0 = r0 + p[i + 0] * p[i + 0];
    r1 = r1 + p[i + 1] * p[i + 1];
    r2 = r2 + p[i + 2] * p[i + 2];
    r3 = r3 + p[i + 3] * p[i + 3];
    r4 = r4 + p[i + 4] * p[i + 4];
    r5 = r5 + p[i + 5] * p[i + 5];
    r6 = r6 + p[i + 6] * p[i + 6];
    r7 = r7 + p[i + 7] * p[i + 7];
  }
  return ((r0 + r1) + (r2 + r3)) + ((r4 + r5) + (r6 + r7));
}

// ---------------------------------------------------------------------------
// Kernel 0: prep (r7 unchanged). 128 blocks.
//   all gtid:    Wt transpose (coalesced read, scattered write)
//   gtid < 4096: W -> MFMA-B-fragment bf16 hi/lo
//   gtid < 512:  wnorm_np[k] (numpy-exact)
//   gtid == 0:   zero ws scalars
// ---------------------------------------------------------------------------
__global__ void k_prep(const float* __restrict__ W, short8* __restrict__ Bh,
                       short8* __restrict__ Bl, float* __restrict__ wnorm,
                       float* __restrict__ Wt, int* __restrict__ flagCnt,
                       int* __restrict__ doneCnt, float* __restrict__ lossSum) {
  int gtid = blockIdx.x * blockDim.x + threadIdx.x;  // 0..32767
  if (gtid == 0) { *flagCnt = 0; *doneCnt = 0; *lossSum = 0.0f; }

  {
    int k = gtid >> 6, d = gtid & 63;
    Wt[(d << 9) + k] = W[(k << 6) + d];
  }

  if (gtid < 4096) {
    int t = gtid >> 7, rem = gtid & 127;
    int h = rem >> 6, L = rem & 63;
    int cw = (t << 4) + (L & 15);
    int dbase = (h << 5) + ((L >> 4) << 3);
    short8 hi, lo;
    cvt8(W + (cw << 6) + dbase, hi, lo);
    Bh[gtid] = hi;  // gtid == ((t*2+h)*64 + L)
    Bl[gtid] = lo;
    if (gtid < KC) wnorm[gtid] = np_sumsq64(W + (gtid << 6));
  }
}

// ---------------------------------------------------------------------------
// Kernel 1: fused MFMA screen + argmin + epilogue.
// ROUND-8: r0 skeleton EXACTLY (MT=4, 4 waves x 64 rows, serial epilogue,
// global flagList — the 93.5us-measured config) with ONE isolated change:
// 2-DEEP REGISTER PREFETCH of the B fragments. Rationale: screen is ~75%
// stalled (VALUBusy 27% @ 2 waves/SIMD, grid-limited); B loads were issued
// at iter top and consumed immediately -> full L2 latency exposed every
// tile. r1/r3/r4 never isolated this lever (each also changed geometry).
// Loop unrolled x2: loads for tiles t+2,t+3 issue BEFORE computes of t,t+1,
// giving each load ~2 tile-bodies to land. +64 VGPR (2nd buffer set) is
// free: grid-limited occupancy, no launch_bounds clamp (r2 lesson).
// ---------------------------------------------------------------------------
#define LDT(T, H0, H1, L0, L1, WN)            \
  {                                           \
    H0 = Bh[(((T)*2 + 0) << 6) + lane];       \
    H1 = Bh[(((T)*2 + 1) << 6) + lane];       \
    L0 = Bl[(((T)*2 + 0) << 6) + lane];       \
    L1 = Bl[(((T)*2 + 1) << 6) + lane];       \
    WN = wnorm[((T) << 4) + m];               \
  }

#define COMPUTE(T, H0, H1, L0, L1, WN)                                                   \
  {                                                                                      \
    f32x4 acc[4] = {{0.f, 0.f, 0.f, 0.f}, {0.f, 0.f, 0.f, 0.f},                          \
                    {0.f, 0.f, 0.f, 0.f}, {0.f, 0.f, 0.f, 0.f}};                         \
    _Pragma("unroll")                                                                    \
    for (int mt = 0; mt < 4; mt++)                                                       \
      acc[mt] = __builtin_amdgcn_mfma_f32_16x16x32_bf16(Ah[mt][0], H0, acc[mt], 0, 0, 0);\
    _Pragma("unroll")                                                                    \
    for (int mt = 0; mt < 4; mt++)                                                       \
      acc[mt] = __builtin_amdgcn_mfma_f32_16x16x32_bf16(Al[mt][0], H0, acc[mt], 0, 0, 0);\
    _Pragma("unroll")                                                                    \
    for (int mt = 0; mt < 4; mt++)                                                       \
      acc[mt] = __builtin_amdgcn_mfma_f32_16x16x32_bf16(Ah[mt][0], L0, acc[mt], 0, 0, 0);\
    _Pragma("unroll")                                                                    \
    for (int mt = 0; mt < 4; mt++)                                                       \
      acc[mt] = __builtin_amdgcn_mfma_f32_16x16x32_bf16(Ah[mt][1], H1, acc[mt], 0, 0, 0);\
    _Pragma("unroll")                                                                    \
    for (int mt = 0; mt < 4; mt++)                                                       \
      acc[mt] = __builtin_amdgcn_mfma_f32_16x16x32_bf16(Al[mt][1], H1, acc[mt], 0, 0, 0);\
    _Pragma("unroll")                                                                    \
    for (int mt = 0; mt < 4; mt++)                                                       \
      acc[mt] = __builtin_amdgcn_mfma_f32_16x16x32_bf16(Ah[mt][1], L1, acc[mt], 0, 0, 0);\
    const int colv = ((T) << 4) + m;                                                     \
    _Pragma("unroll")                                                                    \
    for (int mt = 0; mt < 4; mt++)                                                       \
      _Pragma("unroll")                                                                  \
      for (int r = 0; r < 4; r++) {                                                      \
        float s = fmaf(-2.0f, acc[mt][r], WN);                                           \
        if (s < b1[mt][r]) { b2[mt][r] = b1[mt][r]; b1[mt][r] = s; bi[mt][r] = colv; }   \
        else b2[mt][r] = fminf(b2[mt][r], s);                                            \
      }                                                                                  \
  }

__global__ __launch_bounds__(256) void k_screen(
    const float* __restrict__ z, const float* __restrict__ W,
    const short8* __restrict__ Bh, const short8* __restrict__ Bl,
    const float* __restrict__ wnorm, float* __restrict__ out,
    int* __restrict__ flagList, int* __restrict__ flagCnt,
    float* __restrict__ lossSum) {
  const int lane = threadIdx.x & 63;
  const int wave = threadIdx.x >> 6;
  const int rowBase = blockIdx.x * 256 + wave * 64;
  const int m = lane & 15, quad = lane >> 4;

  // ---- A fragments: zh/zl for 4 M-tiles x 2 k-halves ----
  short8 Ah[4][2], Al[4][2];
#pragma unroll
  for (int mt = 0; mt < 4; mt++) {
    const float* zp = z + (size_t)(rowBase + (mt << 4) + m) * DD + (quad << 3);
#pragma unroll
    for (int h = 0; h < 2; h++) cvt8(zp + (h << 5), Ah[mt][h], Al[mt][h]);
  }

  float b1[4][4], b2[4][4];
  int bi[4][4];
#pragma unroll
  for (int mt = 0; mt < 4; mt++)
#pragma unroll
    for (int r = 0; r < 4; r++) { b1[mt][r] = 1e30f; b2[mt][r] = 1e30f; bi[mt][r] = 0; }

  // ---- main loop, software-pipelined 2 tiles deep ----
  // NOTE accumulation order per tile is r0-identical (same MFMA sequence,
  // same score fmaf) -> bit-identical results; only load timing changed.
  short8 c0h0, c0h1, c0l0, c0l1, c1h0, c1h1, c1l0, c1l1;
  float cw0, cw1;
  LDT(0, c0h0, c0h1, c0l0, c0l1, cw0)
  LDT(1, c1h0, c1h1, c1l0, c1l1, cw1)

  for (int t = 0; t < 30; t += 2) {
    short8 n0h0, n0h1, n0l0, n0l1, n1h0, n1h1, n1l0, n1l1;
    float nw0, nw1;
    LDT(t + 2, n0h0, n0h1, n0l0, n0l1, nw0)
    LDT(t + 3, n1h0, n1h1, n1l0, n1l1, nw1)
    COMPUTE(t,     c0h0, c0h1, c0l0, c0l1, cw0)
    COMPUTE(t + 1, c1h0, c1h1, c1l0, c1l1, cw1)
    c0h0 = n0h0; c0h1 = n0h1; c0l0 = n0l0; c0l1 = n0l1; cw0 = nw0;
    c1h0 = n1h0; c1h1 = n1h1; c1l0 = n1l0; c1l1 = n1l1; cw1 = nw1;
  }
  COMPUTE(30, c0h0, c0h1, c0l0, c0l1, cw0)
  COMPUTE(31, c1h0, c1h1, c1l0, c1l1, cw1)

  // ---- merge across the 16 col-lanes (xor butterfly within quad group) ----
#pragma unroll
  for (int off = 1; off < 16; off <<= 1) {
#pragma unroll
    for (int mt = 0; mt < 4; mt++)
#pragma unroll
      for (int r = 0; r < 4; r++) {
        float o1 = __shfl_xor(b1[mt][r], off, 64);
        float o2 = __shfl_xor(b2[mt][r], off, 64);
        int oi = __shfl_xor(bi[mt][r], off, 64);
        if (o1 < b1[mt][r] || (o1 == b1[mt][r] && oi < bi[mt][r])) {
          b2[mt][r] = fminf(b1[mt][r], o2);
          b1[mt][r] = o1; bi[mt][r] = oi;
        } else {
          b2[mt][r] = fminf(b2[mt][r], o1);
        }
      }
  }

  // ---- fused epilogue: z_q_st, idx, loss, flags (r0 verbatim) ----
  float lossAcc = 0.f;
#pragma unroll
  for (int mt = 0; mt < 4; mt++)
#pragma unroll
    for (int lr = 0; lr < 16; lr++) {
      const int q = lr >> 2, r = lr & 3;
      int ki = __shfl(bi[mt][r], q << 4, 64);
      float b1r = __shfl(b1[mt][r], q << 4, 64);
      float b2r = __shfl(b2[mt][r], q << 4, 64);
      int row = rowBase + (mt << 4) + lr;
      float zv = z[(size_t)row * DD + lane];
      float w = W[(ki << 6) + lane];
      float tt = w - zv;
      float o = zv + tt;  // matches reference z + (z_q - z)
      out[(size_t)row * DD + lane] = o;
      float dl = zv - o;
      lossAcc = fmaf(dl, dl, lossAcc);
      if (lane == 0) {
        out[OUT_IDX_OFF + row] = (float)ki;
        if (b2r - b1r < MARGIN) {
          int slot = atomicAdd(flagCnt, 1);
          if (slot < FLAG_CAP) flagList[slot] = row;
        }
      }
    }

#pragma unroll
  for (int off = 1; off < 64; off <<= 1) lossAcc += __shfl_xor(lossAcc, off, 64);
  if (lane == 0) atomicAdd(lossSum, lossAcc);
}

// ---------------------------------------------------------------------------
// Kernel 2: numpy-f32 replication for flagged rows + patch out/loss
// (r7 unchanged: coalesced Wt dot, last-block-done loss finalize).
// ---------------------------------------------------------------------------
__global__ void k_refine(const float* __restrict__ z, const float* __restrict__ W,
                         const float* __restrict__ Wt, const float* __restrict__ wnp,
                         float* __restrict__ out,
                         const int* __restrict__ flagList,
                         const int* __restrict__ flagCnt,
                         float* __restrict__ lossSum, int* __restrict__ doneCnt) {
  int nflag = *flagCnt;
  if (nflag > FLAG_CAP) nflag = FLAG_CAP;
  int lane = threadIdx.x & 63;
  int wave = (blockIdx.x * blockDim.x + threadIdx.x) >> 6;
  int nWaves = (gridDim.x * blockDim.x) >> 6;

  for (int f = wave; f < nflag; f += nWaves) {
    int row = flagList[f];
    const float* zr = z + (size_t)row * DD;
    float A = np_sumsq64(zr);

    float best = 1e30f;
    int bk = 0x7fffffff;
#pragma unroll
    for (int j = 0; j < KC / 64; j++) {
      int k = lane + (j << 6);
      double cd = 0.0;
      for (int d = 0; d < DD; d++)
        cd = fma((double)zr[d], (double)Wt[(d << 9) + k], cd);
      float twoC = (float)(2.0 * cd);
      float dist;
      {
#pragma clang fp contract(off)
        float t1 = A + wnp[k];
        dist = t1 - twoC;
      }
      if (dist < best || (dist == best && k < bk)) { best = dist; bk = k; }
    }
#pragma unroll
    for (int off = 1; off < 64; off <<= 1) {
      float ov = __shfl_xor(best, off, 64);
      int ok = __shfl_xor(bk, off, 64);
      if (ov < best || (ov == best && ok < bk)) { best = ov; bk = ok; }
    }

    int kold = (int)out[OUT_IDX_OFF + row];
    if (bk != kold) {
      float zv = zr[lane];
      float wN = W[(bk << 6) + lane];
      float oOld = out[(size_t)row * DD + lane];
      float tN = wN - zv;
      float oN = zv + tN;
      out[(size_t)row * DD + lane] = oN;
      float dN = zv - oN, dO = zv - oOld;
      float delta = dN * dN - dO * dO;
#pragma unroll
      for (int off = 1; off < 64; off <<= 1) delta += __shfl_xor(delta, off, 64);
      if (lane == 0) {
        atomicAdd(lossSum, delta);
        out[OUT_IDX_OFF + row] = (float)bk;
      }
    }
  }

  // ---- finalize: last block to arrive writes the loss scalar ----
  __syncthreads();
  if (threadIdx.x == 0) {
    __threadfence();
    int d = atomicAdd(doneCnt, 1);
    if (d == (int)gridDim.x - 1) {
      float s = atomicAdd(lossSum, 0.0f);  // atomic read sees all prior adds
      out[OUT_LOSS_OFF] = 0.25f * s / (float)NELEM;
    }
  }
}

extern "C" void kernel_launch(void* const* d_in, const int* in_sizes, int n_in,
                              void* d_out, int out_size, void* d_ws, size_t ws_size,
                              hipStream_t stream) {
  const float* z = (const float*)d_in[0];
  const float* W = (const float*)d_in[1];
  float* out = (float*)d_out;
  char* ws = (char*)d_ws;

  int* flagCnt = (int*)(ws + WSO_CNT);
  int* doneCnt = (int*)(ws + WSO_DONE);
  float* lossSum = (float*)(ws + WSO_LOSS);
  float* wnorm = (float*)(ws + WSO_WNORM);
  short8* Bh = (short8*)(ws + WSO_BH);
  short8* Bl = (short8*)(ws + WSO_BL);
  float* Wt = (float*)(ws + WSO_WT);
  int* flagList = (int*)(ws + WSO_LIST);

  k_prep<<<128, 256, 0, stream>>>(W, Bh, Bl, wnorm, Wt, flagCnt, doneCnt, lossSum);
  k_screen<<<NROWS / 256, 256, 0, stream>>>(z, W, Bh, Bl, wnorm, out,
                                            flagList, flagCnt, lossSum);
  k_refine<<<256, 256, 0, stream>>>(z, W, Wt, wnorm, out, flagList, flagCnt,
                                    lossSum, doneCnt);
}